// Round 1
// 3034.053 us; speedup vs baseline: 1.1521x; 1.1521x over previous
//
#include <hip/hip_runtime.h>
#include <math.h>

#define SS 512
#define BB 32
#define HH 256
#define G4 1024
#define TT 11
#define NEGV (-1000.0f)

// ---------------- workspace layout (bytes) ----------------
static const size_t OFF_XEH   = 0;                          // 8,388,608  : xe_hi [16384][256] bf16
static const size_t OFF_XEL   = 8388608ull;                 // 8,388,608  : xe_lo
static const size_t OFF_XS    = 16777216ull;                // 134,217,728: xs [2][S][B][1024] f32
static const size_t OFF_H0    = OFF_XS + 134217728ull;      // 33,554,432 : h0 [B*S][512] f32
static const size_t OFF_H1    = OFF_H0 + 33554432ull;       // 33,554,432 : h1 f32 (also h0_hi/h0_lo bf16 before scan1)
static const size_t OFF_FEATS = OFF_H1 + 33554432ull;       // 720,896    : feats [B][S][11]
static const size_t OFF_HGRP  = OFF_FEATS + 720896ull;      // 262,144    : tagged h [2][2][32][256] u64
static const size_t OFF_W0H   = OFF_HGRP + 1048576ull;      // 1,048,576  : wih0 hi [2][1024][256] bf16
static const size_t OFF_W0L   = OFF_W0H + 1048576ull;       // 1,048,576
static const size_t OFF_W1H   = OFF_W0L + 1048576ull;       // 2,097,152  : wih1 hi [2][1024][512] bf16
static const size_t OFF_W1L   = OFF_W1H + 2097152ull;       // 2,097,152
// total ~226 MB

typedef __attribute__((ext_vector_type(8))) short short8;
typedef __attribute__((ext_vector_type(4))) float f32x4;

// fast transcendentals (1-2 ulp; outputs compared in bf16 w/ large threshold)
__device__ __forceinline__ float fsig(float x) {
  return __builtin_amdgcn_rcpf(1.f + __expf(-x));
}
__device__ __forceinline__ float ftanh(float x) {
  return 1.f - 2.f * __builtin_amdgcn_rcpf(__expf(2.f * x) + 1.f);
}

// raw barrier: drains LDS ops only (NO vmcnt(0) drain)
__device__ __forceinline__ void block_sync_lds() {
  asm volatile("s_waitcnt lgkmcnt(0)\n\ts_barrier" ::: "memory");
}

// ---------------- bf16 hi/lo split helpers ----------------
__device__ __forceinline__ unsigned short bfh(float x) {
  unsigned u = __float_as_uint(x);
  unsigned r = u + 0x7fffu + ((u >> 16) & 1u);   // RNE to bf16 (finite inputs)
  return (unsigned short)(r >> 16);
}
__device__ __forceinline__ void split1(float x, unsigned short& h, unsigned short& l) {
  h = bfh(x);
  float hf = __uint_as_float(((unsigned)h) << 16);
  l = bfh(x - hf);
}

// ---------------- embedding gather + split ----------------
__global__ void emb_kernel(const int* __restrict__ x, const float4* __restrict__ emb,
                           ushort4* __restrict__ xeh, ushort4* __restrict__ xel) {
  int idx = blockIdx.x * 256 + threadIdx.x;    // over B*S*64 float4-chunks
  int bs  = idx >> 6;
  int kq  = idx & 63;
  float4 v = emb[(size_t)x[bs] * 64 + kq];
  ushort4 h, l;
  split1(v.x, h.x, l.x); split1(v.y, h.y, l.y);
  split1(v.z, h.z, l.z); split1(v.w, h.w, l.w);
  xeh[idx] = h; xel[idx] = l;
}

// ---------------- generic f32 -> bf16 hi/lo split ----------------
__global__ void split_kernel(const float4* __restrict__ in, ushort4* __restrict__ oh,
                             ushort4* __restrict__ ol, int n4) {
  int i = blockIdx.x * 256 + threadIdx.x;
  if (i < n4) {
    float4 v = in[i];
    ushort4 h, l;
    split1(v.x, h.x, l.x); split1(v.y, h.y, l.y);
    split1(v.z, h.z, l.z); split1(v.w, h.w, l.w);
    oh[i] = h; ol[i] = l;
  }
}

// ---------------- input projection GEMM via split-bf16 MFMA ----------------
// C[m][n] = sum_k A[m][k]*W[n][k] + bias[n], computed as (Ah+Al)(Wh+Wl) with
// 4 bf16 MFMA products (hh+hl+lh+ll), fp32 accumulate -> ~2^-18 rel error.
// Block tile 64m x 128n, 4 waves (2x2), wave tile 32m x 64n = 2x4 MFMA tiles.
// mfma_f32_16x16x32_bf16: A/B frag = 8 bf16 (lane&15 = m/n, k = quad*8+j);
// C/D: col=lane&15, row=quad*4+reg  [verified m89/m91].
template<int K>
__global__ __launch_bounds__(256, 2)
void proj_mfma(const unsigned short* __restrict__ Ah_g, const unsigned short* __restrict__ Al_g,
               const unsigned short* __restrict__ Wh_g, const unsigned short* __restrict__ Wl_g,
               const float* __restrict__ bf, const float* __restrict__ bb,
               float* __restrict__ xs) {
  int tid = threadIdx.x;
  int bm  = blockIdx.x * 64;
  int bn  = blockIdx.y * 128;
  int dir = blockIdx.z;
  const unsigned short* Wh = Wh_g + (size_t)dir * 1024 * K;
  const unsigned short* Wl = Wl_g + (size_t)dir * 1024 * K;
  const float* bias = dir ? bb : bf;
  float* out = xs + (size_t)dir * (SS * BB * G4);

  // rows padded to 40 shorts (80 B): frag reads land 2-way max on banks (free)
  __shared__ unsigned short AhS[64][40], AlS[64][40];
  __shared__ unsigned short BhS[128][40], BlS[128][40];

  int w = tid >> 6, lane = tid & 63;
  int wm = w >> 1, wn = w & 1;
  int fr = lane & 15, q8 = (lane >> 4) * 8;
  int ra = tid >> 2;                 // staging row 0..63
  int ck = (tid & 3) * 8;            // staging chunk: 4 x 8 shorts = 32 shorts/row

  f32x4 acc[2][4];
  #pragma unroll
  for (int mt = 0; mt < 2; mt++)
    #pragma unroll
    for (int nt = 0; nt < 4; nt++) acc[mt][nt] = 0;

  for (int k0 = 0; k0 < K; k0 += 32) {
    __syncthreads();
    // A: 64 rows x 32 shorts (1 uint4 store/thread per matrix)
    *(uint4*)&AhS[ra][ck] = *(const uint4*)(Ah_g + (size_t)(bm + ra) * K + k0 + ck);
    *(uint4*)&AlS[ra][ck] = *(const uint4*)(Al_g + (size_t)(bm + ra) * K + k0 + ck);
    // B: 128 rows x 32 shorts (2 uint4 stores/thread per matrix)
    *(uint4*)&BhS[ra][ck]      = *(const uint4*)(Wh + (size_t)(bn + ra) * K + k0 + ck);
    *(uint4*)&BhS[ra + 64][ck] = *(const uint4*)(Wh + (size_t)(bn + ra + 64) * K + k0 + ck);
    *(uint4*)&BlS[ra][ck]      = *(const uint4*)(Wl + (size_t)(bn + ra) * K + k0 + ck);
    *(uint4*)&BlS[ra + 64][ck] = *(const uint4*)(Wl + (size_t)(bn + ra + 64) * K + k0 + ck);
    __syncthreads();

    short8 ah[2], al[2], bh[4], bl[4];
    #pragma unroll
    for (int mt = 0; mt < 2; mt++) {
      ah[mt] = *(const short8*)&AhS[wm * 32 + mt * 16 + fr][q8];
      al[mt] = *(const short8*)&AlS[wm * 32 + mt * 16 + fr][q8];
    }
    #pragma unroll
    for (int nt = 0; nt < 4; nt++) {
      bh[nt] = *(const short8*)&BhS[wn * 64 + nt * 16 + fr][q8];
      bl[nt] = *(const short8*)&BlS[wn * 64 + nt * 16 + fr][q8];
    }
    #pragma unroll
    for (int mt = 0; mt < 2; mt++)
      #pragma unroll
      for (int nt = 0; nt < 4; nt++) {
        acc[mt][nt] = __builtin_amdgcn_mfma_f32_16x16x32_bf16(ah[mt], bh[nt], acc[mt][nt], 0, 0, 0);
        acc[mt][nt] = __builtin_amdgcn_mfma_f32_16x16x32_bf16(ah[mt], bl[nt], acc[mt][nt], 0, 0, 0);
        acc[mt][nt] = __builtin_amdgcn_mfma_f32_16x16x32_bf16(al[mt], bh[nt], acc[mt][nt], 0, 0, 0);
        acc[mt][nt] = __builtin_amdgcn_mfma_f32_16x16x32_bf16(al[mt], bl[nt], acc[mt][nt], 0, 0, 0);
      }
  }

  // epilogue: C/D col = lane&15 (n), row = quad*4+reg (m); out[(s*B+b)*1024+n]
  #pragma unroll
  for (int mt = 0; mt < 2; mt++)
    #pragma unroll
    for (int nt = 0; nt < 4; nt++) {
      int n  = bn + wn * 64 + nt * 16 + fr;
      float bv = bias[n];
      int mbase = bm + wm * 32 + mt * 16 + (lane >> 4) * 4;
      #pragma unroll
      for (int r = 0; r < 4; r++) {
        int mm = mbase + r;
        int b_ = mm >> 9;
        int s_ = mm & 511;
        out[(size_t)(s_ * BB + b_) * G4 + n] = acc[mt][nt][r] + bv;
      }
    }
}

// ---------------- recurrent scan (R9: producer-direct, 256 blocks) ----------------
// Restructure vs R6: grid (8 cg, 16 bg, 2 dir) = 256 blocks (1/CU), 4 waves,
// 2 batches/block. K is split across lane-halves (not waves): lane = 32*ks + r,
// r = gate*8 + cellofs, ks = k-half. Each lane holds 128 weight floats (1 row x
// 128 k). Full sums via one shfl_xor(32); gate transpose via 4 shfl; 16 lanes/
// wave then do the cell update + tagged store directly. No consumer wave, no
// LDS partial exchange, one lgkm-barrier per step.
// Sync protocol unchanged from the verified kernel: tagged u64 {tag=s+1, h bits}
// in hgrp[dir][parity][batch][cell], parity double-buffer, memset-0 init (tag 0
// == initial h=0). Per-block barrier + all-col polling bounds skew to 1 step,
// so slots (reused every 2 steps) are never overwritten before their readers
// pass — same invariants as R6.
__global__ __launch_bounds__(256, 1)
void scan_kernel(const float* __restrict__ xs,      // [2][S][B][1024]
                 const float* __restrict__ whhf, const float* __restrict__ whhb,
                 unsigned long long* __restrict__ hgrp,  // [2][2][32][256] u64
                 float* __restrict__ hout)          // [B*S][512]
{
  int tid  = threadIdx.x;
  int w    = tid >> 6;          // wave 0..3
  int lane = tid & 63;
  int cg   = blockIdx.x;        // cell group 0..7 (32 cells)
  int bg   = blockIdx.y;        // batch pair 0..15 (2 batches)
  int dir  = blockIdx.z;
  const float* xsd = xs + (size_t)dir * (SS * BB * G4);
  const float* whh = dir ? whhb : whhf;
  unsigned long long* hg = hgrp + (size_t)dir * 16384;   // [2][32][256]

  __shared__ float h_sh[2][2][256];   // [parity][local batch][cell]

  int r    = lane & 31;         // row within wave's 32 rows: gate*8 + cellofs
  int ks   = lane >> 5;         // k-half: 0 -> k<128, 1 -> k>=128
  int g    = r >> 3;            // gate 0..3 (i,f,g,o)
  int c7   = r & 7;
  int cell = cg * 32 + w * 8 + c7;   // global cell of this lane's row
  int grow = g * 256 + cell;         // whh row

  // weights: 1 row x 128 k = 32 float4 in VGPRs
  float4 wreg[32];
  {
    const float* wp = whh + (size_t)grow * 256 + ks * 128;
    #pragma unroll
    for (int j = 0; j < 32; j++) wreg[j] = *(const float4*)(wp + j * 4);
  }

  int b0  = bg * 2;
  int col = tid & 255;          // polled cell column (w*64+lane)
  bool ul = (r < 8);            // update lane: owns (cell, batch b0+ks)
  int ub  = b0 + ks;
  float cst = 0.f;              // c-state for the owned cell
  float xf[4];                  // prefetched x-projection (4 gates)
  if (ul) {
    int t0 = dir ? (SS - 1) : 0;
    const float* xp = xsd + (size_t)(t0 * BB + ub) * G4 + cell;
    #pragma unroll
    for (int i = 0; i < 4; i++) xf[i] = xp[i * 256];
  }

  for (int s = 0; s < SS; ++s) {
    int p = s & 1;
    const unsigned long long* src = hg + ((size_t)(p * 32 + b0) * 256 + col);
    // spin for tag==s on both batches; keep a poll generation in flight
    unsigned long long rv0 = __hip_atomic_load(src,       __ATOMIC_RELAXED, __HIP_MEMORY_SCOPE_AGENT);
    unsigned long long rv1 = __hip_atomic_load(src + 256, __ATOMIC_RELAXED, __HIP_MEMORY_SCOPE_AGENT);
    for (;;) {
      unsigned long long n0 = __hip_atomic_load(src,       __ATOMIC_RELAXED, __HIP_MEMORY_SCOPE_AGENT);
      unsigned long long n1 = __hip_atomic_load(src + 256, __ATOMIC_RELAXED, __HIP_MEMORY_SCOPE_AGENT);
      unsigned t = ((unsigned)(rv0 >> 32) ^ (unsigned)s) |
                   ((unsigned)(rv1 >> 32) ^ (unsigned)s);
      if (__all(t == 0u)) break;
      rv0 = n0; rv1 = n1;
    }
    h_sh[p][0][col] = __uint_as_float((unsigned)rv0);
    h_sh[p][1][col] = __uint_as_float((unsigned)rv1);
    block_sync_lds();

    // matvec: 1 row x 2 batches x 128 k per lane (h reads are wave-uniform
    // per half -> LDS broadcast, conflict-free)
    float acc0 = 0.f, acc1 = 0.f;
    const float* hb0 = &h_sh[p][0][ks * 128];
    const float* hb1 = &h_sh[p][1][ks * 128];
    #pragma unroll
    for (int j = 0; j < 32; j++) {
      float4 hv0 = *(const float4*)(hb0 + j * 4);
      float4 hv1 = *(const float4*)(hb1 + j * 4);
      float4 wv  = wreg[j];
      acc0 += wv.x * hv0.x + wv.y * hv0.y + wv.z * hv0.z + wv.w * hv0.w;
      acc1 += wv.x * hv1.x + wv.y * hv1.y + wv.z * hv1.z + wv.w * hv1.w;
    }
    // combine k-halves (lane <-> lane^32 hold same row, complementary k)
    acc0 += __shfl_xor(acc0, 32, 64);
    acc1 += __shfl_xor(acc1, 32, 64);
    // half h (ks) carries batch b0+ks from here on
    float v = ks ? acc1 : acc0;
    // gather the 4 gates of this lane's cell from rows g*8+c in the same half
    float gv[4];
    #pragma unroll
    for (int gg = 0; gg < 4; gg++)
      gv[gg] = __shfl(v, (lane & 32) + gg * 8 + (lane & 7), 64);

    if (ul) {
      float ig = fsig(gv[0] + xf[0]);
      float fg = fsig(gv[1] + xf[1]);
      float gt = ftanh(gv[2] + xf[2]);
      float og = fsig(gv[3] + xf[3]);
      cst = fg * cst + ig * gt;
      float hv = og * ftanh(cst);
      unsigned hb = __float_as_uint(hv);
      unsigned long long tagw = ((unsigned long long)(unsigned)(s + 1) << 32) | hb;
      __hip_atomic_store(hg + ((size_t)(((s + 1) & 1) * 32 + ub) * 256 + cell), tagw,
                         __ATOMIC_RELAXED, __HIP_MEMORY_SCOPE_AGENT);
      int tpos = dir ? (SS - 1 - s) : s;
      hout[((size_t)(ub * SS + tpos)) * 512 + dir * 256 + cell] = hv;
      if (s + 1 < SS) {
        int tpn = dir ? (SS - 2 - s) : (s + 1);
        const float* xp = xsd + (size_t)(tpn * BB + ub) * G4 + cell;
        #pragma unroll
        for (int i = 0; i < 4; i++) xf[i] = xp[i * 256];
      }
    }
  }
}

// ---------------- emission features ----------------
__global__ void feats_kernel(const float* __restrict__ h1, const float* __restrict__ wout,
                             const float* __restrict__ bout, float* __restrict__ feats) {
  int bs = blockIdx.x;
  int lane = threadIdx.x;
  const float* hp = h1 + (size_t)bs * 512;
  float hv[8];
  #pragma unroll
  for (int i = 0; i < 8; i++) hv[i] = hp[lane + i * 64];
  #pragma unroll
  for (int t = 0; t < TT; t++) {
    const float* wp = wout + t * 512;
    float p = 0.f;
    #pragma unroll
    for (int i = 0; i < 8; i++) p += hv[i] * wp[lane + i * 64];
    #pragma unroll
    for (int off = 32; off >= 1; off >>= 1) p += __shfl_down(p, off, 64);
    if (lane == 0) feats[(size_t)bs * TT + t] = p + bout[t];
  }
}

// ---------------- Viterbi decode ----------------
__global__ void viterbi_kernel(const float* __restrict__ feats, const float* __restrict__ trans,
                               float* __restrict__ out) {
  int b = blockIdx.x;
  int lane = threadIdx.x;
  __shared__ float tr[121];
  __shared__ float fch[32 * TT];
  __shared__ unsigned char bp[SS][12];
  __shared__ unsigned char path[SS];
  for (int i = lane; i < 121; i += 64) tr[i] = trans[i];
  __syncthreads();
  int ln = lane < TT ? lane : (TT - 1);
  float trr[TT];
  #pragma unroll
  for (int p = 0; p < TT; p++) trr[p] = tr[ln * TT + p];
  float fv = (lane == 9) ? 0.f : NEGV;   // START = 9
  const float* fb = feats + (size_t)b * SS * TT;

  for (int s = 0; s < SS; s++) {
    if ((s & 31) == 0) {
      __syncthreads();
      for (int i = lane; i < 32 * TT; i += 64) fch[i] = fb[s * TT + i];
      __syncthreads();
    }
    float best = -3.0e38f; int arg = 0;
    #pragma unroll
    for (int p = 0; p < TT; p++) {
      float v = __shfl(fv, p, 64) + trr[p];
      if (v > best) { best = v; arg = p; }   // strict > keeps FIRST max (numpy argmax)
    }
    if (lane < TT) bp[s][lane] = (unsigned char)arg;
    fv = best + fch[(s & 31) * TT + ln];
  }
  float term = fv + tr[10 * TT + ln];        // STOP = 10
  float best = -3.0e38f; int arg = 0;
  #pragma unroll
  for (int p = 0; p < TT; p++) {
    float v = __shfl(term, p, 64);
    if (v > best) { best = v; arg = p; }
  }
  __syncthreads();
  if (lane == 0) {
    out[b] = best;
    int tg = arg;
    path[SS - 1] = (unsigned char)tg;
    for (int s = SS - 1; s >= 1; s--) {
      tg = bp[s][tg];
      path[s - 1] = (unsigned char)tg;
    }
  }
  __syncthreads();
  for (int i = lane; i < SS; i += 64) out[32 + b * SS + i] = (float)path[i];
}

// ---------------- launcher ----------------
extern "C" void kernel_launch(void* const* d_in, const int* in_sizes, int n_in,
                              void* d_out, int out_size, void* d_ws, size_t ws_size,
                              hipStream_t stream) {
  const int*   x     = (const int*)d_in[0];
  const float* emb   = (const float*)d_in[2];
  const float* wih0f = (const float*)d_in[3];
  const float* whh0f = (const float*)d_in[4];
  const float* b0f   = (const float*)d_in[5];
  const float* wih0b = (const float*)d_in[6];
  const float* whh0b = (const float*)d_in[7];
  const float* b0b   = (const float*)d_in[8];
  const float* wih1f = (const float*)d_in[9];
  const float* whh1f = (const float*)d_in[10];
  const float* b1f   = (const float*)d_in[11];
  const float* wih1b = (const float*)d_in[12];
  const float* whh1b = (const float*)d_in[13];
  const float* b1b   = (const float*)d_in[14];
  const float* wout  = (const float*)d_in[15];
  const float* bout  = (const float*)d_in[16];
  const float* trans = (const float*)d_in[17];

  char* ws = (char*)d_ws;
  unsigned short* xeh = (unsigned short*)(ws + OFF_XEH);
  unsigned short* xel = (unsigned short*)(ws + OFF_XEL);
  float* xs    = (float*)(ws + OFF_XS);
  float* h0    = (float*)(ws + OFF_H0);
  float* h1    = (float*)(ws + OFF_H1);
  unsigned short* h0h = (unsigned short*)(ws + OFF_H1);               // overlay (dead until scan1)
  unsigned short* h0l = (unsigned short*)(ws + OFF_H1 + 16777216ull);
  float* feats = (float*)(ws + OFF_FEATS);
  unsigned long long* hgrp = (unsigned long long*)(ws + OFF_HGRP);
  unsigned short* w0h = (unsigned short*)(ws + OFF_W0H);
  unsigned short* w0l = (unsigned short*)(ws + OFF_W0L);
  unsigned short* w1h = (unsigned short*)(ws + OFF_W1H);
  unsigned short* w1l = (unsigned short*)(ws + OFF_W1L);
  float* outp  = (float*)d_out;

  // embedding gather + hi/lo split
  emb_kernel<<<4096, 256, 0, stream>>>(x, (const float4*)emb, (ushort4*)xeh, (ushort4*)xel);
  // weight splits: wih0 [2][1024][256], wih1 [2][1024][512]
  split_kernel<<<256, 256, 0, stream>>>((const float4*)wih0f, (ushort4*)w0h, (ushort4*)w0l, 65536);
  split_kernel<<<256, 256, 0, stream>>>((const float4*)wih0b, (ushort4*)(w0h + 262144),
                                        (ushort4*)(w0l + 262144), 65536);
  split_kernel<<<512, 256, 0, stream>>>((const float4*)wih1f, (ushort4*)w1h, (ushort4*)w1l, 131072);
  split_kernel<<<512, 256, 0, stream>>>((const float4*)wih1b, (ushort4*)(w1h + 524288),
                                        (ushort4*)(w1l + 524288), 131072);

  proj_mfma<256><<<dim3(256, 8, 2), 256, 0, stream>>>(xeh, xel, w0h, w0l, b0f, b0b, xs);
  hipMemsetAsync(hgrp, 0, 262144, stream);   // tag 0 == initial h(0) = 0, both parities
  scan_kernel<<<dim3(8, 16, 2), 256, 0, stream>>>(xs, whh0f, whh0b, hgrp, h0);

  split_kernel<<<8192, 256, 0, stream>>>((const float4*)h0, (ushort4*)h0h, (ushort4*)h0l, 2097152);
  proj_mfma<512><<<dim3(256, 8, 2), 256, 0, stream>>>(h0h, h0l, w1h, w1l, b1f, b1b, xs);
  hipMemsetAsync(hgrp, 0, 262144, stream);
  scan_kernel<<<dim3(8, 16, 2), 256, 0, stream>>>(xs, whh1f, whh1b, hgrp, h1);

  feats_kernel<<<BB * SS, 64, 0, stream>>>(h1, wout, bout, feats);
  viterbi_kernel<<<BB, 64, 0, stream>>>(feats, trans, outp);
}